// Round 9
// baseline (271.567 us; speedup 1.0000x reference)
//
#include <hip/hip_runtime.h>
#include <hip/hip_bf16.h>

#define BLOCK 256

__device__ __forceinline__ float frcp(float x) { return __builtin_amdgcn_rcpf(x); }
__device__ __forceinline__ float fsqrt(float x) { return __builtin_amdgcn_sqrtf(x); }
__device__ __forceinline__ float frsq(float x) { return __builtin_amdgcn_rsqf(x); }

// fast acos: Abramowitz-Stegun 4.4.45, abs err ~6.7e-5 rad
__device__ __forceinline__ float facos(float x) {
    float ax = fabsf(x);
    float sq = fsqrt(fmaxf(1.0f - ax, 0.0f));
    float poly = fmaf(fmaf(fmaf(-0.0187293f, ax, 0.0742610f), ax, -0.2121144f),
                      ax, 1.5707288f);
    float ac = sq * poly;
    return (x < 0.0f) ? (3.14159274f - ac) : ac;
}

// logm of a symmetric 3x3 SPD matrix, 6 unique entries {00,01,02,11,12,22}.
__device__ __forceinline__ void logm3(const float m[6], float L[6]) {
    float a00 = m[0], a01 = m[1], a02 = m[2];
    float a11 = m[3], a12 = m[4], a22 = m[5];

    float q  = (a00 + a11 + a22) * (1.0f / 3.0f);
    float b00 = a00 - q, b11 = a11 - q, b22 = a22 - q;
    float p2 = b00*b00 + b11*b11 + b22*b22
             + 2.0f * (a01*a01 + a02*a02 + a12*a12);
    float u  = fmaxf(p2 * (1.0f / 6.0f), 1e-24f);
    float ip = frsq(u);                 // 1/p
    float p  = u * ip;                  // p = sqrt(u)
    float detB = b00*(b11*b22 - a12*a12)
               - a01*(a01*b22 - a12*a02)
               + a02*(a01*a12 - b11*a02);
    float ip3 = ip * ip * ip;
    float r = fminf(fmaxf(0.5f * detB * ip3, -1.0f), 1.0f);
    float phi = facos(r) * (1.0f / 3.0f);
    float sph = __sinf(phi), cph = __cosf(phi);
    float whi = q + 2.0f * p * cph;
    float wlo = q - p * (cph + 1.7320508f * sph);
    float wmid = 3.0f * q - whi - wlo;
    float w0 = fmaxf(wlo,  1e-8f);
    float w1 = fmaxf(wmid, 1e-8f);
    float w2 = fmaxf(whi,  1e-8f);

    float l0 = __logf(w0), l1 = __logf(w1), l2 = __logf(w2);
    float e = 1e-4f * w2;
    float d01 = fmaxf(w1 - w0, e);
    float d12 = fmaxf(w2 - w1, e);
    float d02 = fmaxf(w2 - w0, e);
    float rP = frcp(d01 * d12 * d02);               // single reciprocal
    float dd01 = (l1 - l0) * (d12 * d02) * rP;      // (l1-l0)/d01
    float dd12 = (l2 - l1) * (d01 * d02) * rP;      // (l2-l1)/d12
    float dd012 = (dd12 - dd01) * (d01 * d12) * rP; // (dd12-dd01)/d02
    float k2 = dd012;
    float k1 = dd01 - dd012 * (w0 + w1);
    float k0 = l0 - dd01 * w0 + dd012 * (w0 * w1);

    float s00 = a00*a00 + a01*a01 + a02*a02;
    float s01 = a00*a01 + a01*a11 + a02*a12;
    float s02 = a00*a02 + a01*a12 + a02*a22;
    float s11 = a01*a01 + a11*a11 + a12*a12;
    float s12 = a01*a02 + a11*a12 + a12*a22;
    float s22 = a02*a02 + a12*a12 + a22*a22;

    L[0] = k0 + k1*a00 + k2*s00;
    L[1] =      k1*a01 + k2*s01;
    L[2] =      k1*a02 + k2*s02;
    L[3] = k0 + k1*a11 + k2*s11;
    L[4] =      k1*a12 + k2*s12;
    L[5] = k0 + k1*a22 + k2*s22;
}

__device__ __forceinline__ void load6(const float* __restrict__ a, float m[6]) {
    m[0] = a[0]; m[1] = a[1]; m[2] = a[2];
    m[3] = a[4]; m[4] = a[5]; m[5] = a[8];
}

__device__ __forceinline__ float fnorm2_diff(const float L1[6], const float L2[6]) {
    float d0 = L1[0]-L2[0], d1 = L1[1]-L2[1], d2 = L1[2]-L2[2];
    float d3 = L1[3]-L2[3], d4 = L1[4]-L2[4], d5 = L1[5]-L2[5];
    return d0*d0 + d3*d3 + d5*d5 + 2.0f * (d1*d1 + d2*d2 + d4*d4);
}

__device__ __forceinline__ float pairdist(const float m1[6], const float m2[6]) {
    float L1[6], L2[6];
    logm3(m1, L1);
    logm3(m2, L2);
    return fnorm2_diff(L1, L2);
}

// Single fused kernel: one pair per thread; last-finished block reduces the
// block partials (fixed order, double accum -> deterministic value).
__global__ void __launch_bounds__(BLOCK)
le_fused(const float* __restrict__ D1, const float* __restrict__ D2,
         float* __restrict__ out, unsigned int* __restrict__ counter,
         float* __restrict__ partials, int n, int nblocks, double invN) {
    const int tid = threadIdx.x;
    const long stride = (long)nblocks * BLOCK;
    float acc = 0.0f;

    for (long i = (long)blockIdx.x * BLOCK + tid; i < n; i += stride) {
        float m1[6], m2[6];
        load6(D1 + i * 9, m1);
        load6(D2 + i * 9, m2);
        acc += pairdist(m1, m2);
    }

    // block reduce
    #pragma unroll
    for (int off = 32; off > 0; off >>= 1)
        acc += __shfl_down(acc, off, 64);
    __shared__ float wsum[BLOCK / 64];
    if ((tid & 63) == 0) wsum[tid >> 6] = acc;
    __syncthreads();

    __shared__ int s_last;
    if (tid == 0) {
        float s = 0.0f;
        #pragma unroll
        for (int j = 0; j < BLOCK / 64; ++j) s += wsum[j];
        partials[blockIdx.x] = s;
        __threadfence();                            // publish partial (device scope)
        unsigned int prev = atomicAdd(counter, 1u); // device-scope atomic
        s_last = (prev == (unsigned int)(nblocks - 1));
    }
    __syncthreads();

    if (s_last) {                                   // exactly one block enters
        __threadfence();                            // acquire all partials
        double s = 0.0;
        for (int j = tid; j < nblocks; j += BLOCK)
            s += (double)partials[j];
        #pragma unroll
        for (int off = 32; off > 0; off >>= 1)
            s += __shfl_down(s, off, 64);
        __shared__ double fs[BLOCK / 64];
        if ((tid & 63) == 0) fs[tid >> 6] = s;
        __syncthreads();
        if (tid == 0) {
            double t = 0.0;
            #pragma unroll
            for (int j = 0; j < BLOCK / 64; ++j) t += fs[j];
            out[0] = (float)(t * invN);
        }
    }
}

extern "C" void kernel_launch(void* const* d_in, const int* in_sizes, int n_in,
                              void* d_out, int out_size, void* d_ws, size_t ws_size,
                              hipStream_t stream) {
    const float* D1 = (const float*)d_in[0];
    const float* D2 = (const float*)d_in[1];
    float* out = (float*)d_out;
    unsigned int* counter = (unsigned int*)d_ws;          // d_ws[0]
    float* partials = (float*)d_ws + 1;                   // d_ws[1..nblocks]

    int n = in_sizes[0] / 9;
    int nblocks = (n + BLOCK - 1) / BLOCK;                // 1 pair per thread
    int cap = (int)(ws_size / sizeof(float)) - 2;
    if (cap > 0 && nblocks > cap) nblocks = cap;          // loop covers remainder
    if (nblocks < 1) nblocks = 1;

    hipMemsetAsync(d_ws, 0, sizeof(unsigned int), stream);  // zero the counter
    le_fused<<<nblocks, BLOCK, 0, stream>>>(D1, D2, out, counter, partials,
                                            n, nblocks, 1.0 / (double)n);
}

// Round 10
// 34.759 us; speedup vs baseline: 7.8129x; 7.8129x over previous
//
#include <hip/hip_runtime.h>
#include <hip/hip_bf16.h>

#define BLOCK 256
#define GRID  2048

__device__ __forceinline__ float frcp(float x) { return __builtin_amdgcn_rcpf(x); }
__device__ __forceinline__ float fsqrt(float x) { return __builtin_amdgcn_sqrtf(x); }
__device__ __forceinline__ float frsq(float x) { return __builtin_amdgcn_rsqf(x); }

// fast acos: Abramowitz-Stegun 4.4.45, abs err ~6.7e-5 rad
__device__ __forceinline__ float facos(float x) {
    float ax = fabsf(x);
    float sq = fsqrt(fmaxf(1.0f - ax, 0.0f));
    float poly = fmaf(fmaf(fmaf(-0.0187293f, ax, 0.0742610f), ax, -0.2121144f),
                      ax, 1.5707288f);
    float ac = sq * poly;
    return (x < 0.0f) ? (3.14159274f - ac) : ac;
}

// logm of a symmetric 3x3 SPD matrix, 6 unique entries {00,01,02,11,12,22}.
// Eigenvalues >= 0.5 by construction (M M^T + 0.5 I): minimal guards only.
__device__ __forceinline__ void logm3(const float m[6], float L[6]) {
    float a00 = m[0], a01 = m[1], a02 = m[2];
    float a11 = m[3], a12 = m[4], a22 = m[5];

    float q  = (a00 + a11 + a22) * (1.0f / 3.0f);
    float b00 = a00 - q, b11 = a11 - q, b22 = a22 - q;
    float p2 = b00*b00 + b11*b11 + b22*b22
             + 2.0f * (a01*a01 + a02*a02 + a12*a12);
    float u  = fmaxf(p2 * (1.0f / 6.0f), 1e-24f);
    float ip = frsq(u);                 // 1/p
    float p  = u * ip;                  // p = sqrt(u)
    float detB = b00*(b11*b22 - a12*a12)
               - a01*(a01*b22 - a12*a02)
               + a02*(a01*a12 - b11*a02);
    float ip3 = ip * ip * ip;
    float r = fminf(fmaxf(0.5f * detB * ip3, -1.0f), 1.0f);
    float phi = facos(r) * (1.0f / 3.0f);
    float sph = __sinf(phi), cph = __cosf(phi);
    float whi = q + 2.0f * p * cph;
    float wlo = q - p * (cph + 1.7320508f * sph);
    float wmid = 3.0f * q - whi - wlo;
    float w0 = fmaxf(wlo, 1e-6f);       // >=0.5 in exact arithmetic; cheap guard
    float w1 = wmid;
    float w2 = whi;

    float l0 = __logf(w0), l1 = __logf(w1), l2 = __logf(w2);
    float e = 1e-4f * w2;
    float d01 = fmaxf(w1 - w0, e);
    float d12 = fmaxf(w2 - w1, e);
    float d02 = fmaxf(w2 - w0, e);
    float rP = frcp(d01 * d12 * d02);               // single reciprocal
    float dd01 = (l1 - l0) * (d12 * d02) * rP;      // (l1-l0)/d01
    float dd12 = (l2 - l1) * (d01 * d02) * rP;      // (l2-l1)/d12
    float dd012 = (dd12 - dd01) * (d01 * d12) * rP; // (dd12-dd01)/d02
    float k2 = dd012;
    float k1 = dd01 - dd012 * (w0 + w1);
    float k0 = l0 - dd01 * w0 + dd012 * (w0 * w1);

    float s00 = a00*a00 + a01*a01 + a02*a02;
    float s01 = a00*a01 + a01*a11 + a02*a12;
    float s02 = a00*a02 + a01*a12 + a02*a22;
    float s11 = a01*a01 + a11*a11 + a12*a12;
    float s12 = a01*a02 + a11*a12 + a12*a22;
    float s22 = a02*a02 + a12*a12 + a22*a22;

    L[0] = k0 + k1*a00 + k2*s00;
    L[1] =      k1*a01 + k2*s01;
    L[2] =      k1*a02 + k2*s02;
    L[3] = k0 + k1*a11 + k2*s11;
    L[4] =      k1*a12 + k2*s12;
    L[5] = k0 + k1*a22 + k2*s22;
}

// 32-bit offset load: base uniform (SGPR pair), off9 = 9*i fits int for n=2M.
// Avoids per-lane 64-bit address chains (v_lshl_add_u64 x12 per pair).
__device__ __forceinline__ void load6i(const float* __restrict__ base, int off9,
                                       float m[6]) {
    __builtin_assume(off9 >= 0);
    m[0] = base[off9 + 0]; m[1] = base[off9 + 1]; m[2] = base[off9 + 2];
    m[3] = base[off9 + 4]; m[4] = base[off9 + 5]; m[5] = base[off9 + 8];
}

__device__ __forceinline__ float fnorm2_diff(const float L1[6], const float L2[6]) {
    float d0 = L1[0]-L2[0], d1 = L1[1]-L2[1], d2 = L1[2]-L2[2];
    float d3 = L1[3]-L2[3], d4 = L1[4]-L2[4], d5 = L1[5]-L2[5];
    return d0*d0 + d3*d3 + d5*d5 + 2.0f * (d1*d1 + d2*d2 + d4*d4);
}

__device__ __forceinline__ float pairdist(const float m1[6], const float m2[6]) {
    float L1[6], L2[6];
    logm3(m1, L1);
    logm3(m2, L2);
    return fnorm2_diff(L1, L2);
}

__global__ void __launch_bounds__(BLOCK)
le_partial(const float* __restrict__ D1, const float* __restrict__ D2,
           float* __restrict__ partial, int n) {
    const int tid = threadIdx.x;
    const int T = (int)gridDim.x * BLOCK;      // 524,288 threads at GRID=2048
    float acc = 0.0f;

    // Two pairs per iteration (i, i+T): two independent logm3 chains per
    // thread per loop body -> ILP covers trans-pipe + load latency.
    for (int base = (int)blockIdx.x * BLOCK + tid; base < n; base += 2 * T) {
        int ia = base;
        int ib = base + T;
        bool hb = (ib < n);
        int ibc = hb ? ib : ia;                // clamp: safe load, masked add

        float m1a[6], m2a[6], m1b[6], m2b[6];
        load6i(D1, 9 * ia,  m1a);
        load6i(D2, 9 * ia,  m2a);
        load6i(D1, 9 * ibc, m1b);
        load6i(D2, 9 * ibc, m2b);

        acc += pairdist(m1a, m2a);
        float db = pairdist(m1b, m2b);
        acc += hb ? db : 0.0f;
    }

    // wave reduce (wave = 64)
    #pragma unroll
    for (int off = 32; off > 0; off >>= 1)
        acc += __shfl_down(acc, off, 64);
    __shared__ float wsum[BLOCK / 64];
    if ((tid & 63) == 0) wsum[tid >> 6] = acc;
    __syncthreads();
    if (tid == 0) {
        float s = 0.0f;
        #pragma unroll
        for (int j = 0; j < BLOCK / 64; ++j) s += wsum[j];
        partial[blockIdx.x] = s;
    }
}

__global__ void __launch_bounds__(BLOCK)
le_final(const float* __restrict__ partial, int nparts,
         float* __restrict__ out, double invN) {
    double s = 0.0;
    for (int i = threadIdx.x; i < nparts; i += BLOCK)
        s += (double)partial[i];
    #pragma unroll
    for (int off = 32; off > 0; off >>= 1)
        s += __shfl_down(s, off, 64);
    __shared__ double ws[BLOCK / 64];
    if ((threadIdx.x & 63) == 0) ws[threadIdx.x >> 6] = s;
    __syncthreads();
    if (threadIdx.x == 0) {
        double t = 0.0;
        #pragma unroll
        for (int i = 0; i < BLOCK / 64; ++i) t += ws[i];
        out[0] = (float)(t * invN);
    }
}

extern "C" void kernel_launch(void* const* d_in, const int* in_sizes, int n_in,
                              void* d_out, int out_size, void* d_ws, size_t ws_size,
                              hipStream_t stream) {
    const float* D1 = (const float*)d_in[0];
    const float* D2 = (const float*)d_in[1];
    float* out = (float*)d_out;
    float* partial = (float*)d_ws;

    int n = in_sizes[0] / 9;
    int grid = GRID;
    int nblk = (n + BLOCK - 1) / BLOCK;
    if (grid > nblk) grid = nblk;
    int maxblocks = (int)(ws_size / sizeof(float));
    if (maxblocks > 0 && grid > maxblocks) grid = maxblocks;
    if (grid < 1) grid = 1;

    le_partial<<<grid, BLOCK, 0, stream>>>(D1, D2, partial, n);
    le_final<<<1, BLOCK, 0, stream>>>(partial, grid, out, 1.0 / (double)n);
}

// Round 11
// 31.012 us; speedup vs baseline: 8.7568x; 1.1208x over previous
//
#include <hip/hip_runtime.h>
#include <hip/hip_bf16.h>

#define BLOCK 256
#define FBLOCK 1024

__device__ __forceinline__ float frcp(float x) { return __builtin_amdgcn_rcpf(x); }
__device__ __forceinline__ float fsqrt(float x) { return __builtin_amdgcn_sqrtf(x); }
__device__ __forceinline__ float frsq(float x) { return __builtin_amdgcn_rsqf(x); }

// fast acos: Abramowitz-Stegun 4.4.45, abs err ~6.7e-5 rad
__device__ __forceinline__ float facos(float x) {
    float ax = fabsf(x);
    float sq = fsqrt(fmaxf(1.0f - ax, 0.0f));
    float poly = fmaf(fmaf(fmaf(-0.0187293f, ax, 0.0742610f), ax, -0.2121144f),
                      ax, 1.5707288f);
    float ac = sq * poly;
    return (x < 0.0f) ? (3.14159274f - ac) : ac;
}

// logm of a symmetric 3x3 SPD matrix, 6 unique entries {00,01,02,11,12,22}.
__device__ __forceinline__ void logm3(const float m[6], float L[6]) {
    float a00 = m[0], a01 = m[1], a02 = m[2];
    float a11 = m[3], a12 = m[4], a22 = m[5];

    float q  = (a00 + a11 + a22) * (1.0f / 3.0f);
    float b00 = a00 - q, b11 = a11 - q, b22 = a22 - q;
    float p2 = b00*b00 + b11*b11 + b22*b22
             + 2.0f * (a01*a01 + a02*a02 + a12*a12);
    float u  = fmaxf(p2 * (1.0f / 6.0f), 1e-24f);
    float ip = frsq(u);                 // 1/p
    float p  = u * ip;                  // p = sqrt(u)
    float detB = b00*(b11*b22 - a12*a12)
               - a01*(a01*b22 - a12*a02)
               + a02*(a01*a12 - b11*a02);
    float ip3 = ip * ip * ip;
    float r = fminf(fmaxf(0.5f * detB * ip3, -1.0f), 1.0f);
    float phi = facos(r) * (1.0f / 3.0f);
    float sph = __sinf(phi), cph = __cosf(phi);
    float whi = q + 2.0f * p * cph;
    float wlo = q - p * (cph + 1.7320508f * sph);
    float wmid = 3.0f * q - whi - wlo;
    float w0 = fmaxf(wlo, 1e-6f);       // >=0.5 in exact arithmetic; cheap guard
    float w1 = wmid;
    float w2 = whi;

    float l0 = __logf(w0), l1 = __logf(w1), l2 = __logf(w2);
    float e = 1e-4f * w2;
    float d01 = fmaxf(w1 - w0, e);
    float d12 = fmaxf(w2 - w1, e);
    float d02 = fmaxf(w2 - w0, e);
    float rP = frcp(d01 * d12 * d02);               // single reciprocal
    float dd01 = (l1 - l0) * (d12 * d02) * rP;      // (l1-l0)/d01
    float dd12 = (l2 - l1) * (d01 * d02) * rP;      // (l2-l1)/d12
    float dd012 = (dd12 - dd01) * (d01 * d12) * rP; // (dd12-dd01)/d02
    float k2 = dd012;
    float k1 = dd01 - dd012 * (w0 + w1);
    float k0 = l0 - dd01 * w0 + dd012 * (w0 * w1);

    float s00 = a00*a00 + a01*a01 + a02*a02;
    float s01 = a00*a01 + a01*a11 + a02*a12;
    float s02 = a00*a02 + a01*a12 + a02*a22;
    float s11 = a01*a01 + a11*a11 + a12*a12;
    float s12 = a01*a02 + a11*a12 + a12*a22;
    float s22 = a02*a02 + a12*a12 + a22*a22;

    L[0] = k0 + k1*a00 + k2*s00;
    L[1] =      k1*a01 + k2*s01;
    L[2] =      k1*a02 + k2*s02;
    L[3] = k0 + k1*a11 + k2*s11;
    L[4] =      k1*a12 + k2*s12;
    L[5] = k0 + k1*a22 + k2*s22;
}

__device__ __forceinline__ void load6i(const float* __restrict__ base, int off9,
                                       float m[6]) {
    __builtin_assume(off9 >= 0);
    m[0] = base[off9 + 0]; m[1] = base[off9 + 1]; m[2] = base[off9 + 2];
    m[3] = base[off9 + 4]; m[4] = base[off9 + 5]; m[5] = base[off9 + 8];
}

__device__ __forceinline__ float fnorm2_diff(const float L1[6], const float L2[6]) {
    float d0 = L1[0]-L2[0], d1 = L1[1]-L2[1], d2 = L1[2]-L2[2];
    float d3 = L1[3]-L2[3], d4 = L1[4]-L2[4], d5 = L1[5]-L2[5];
    return d0*d0 + d3*d3 + d5*d5 + 2.0f * (d1*d1 + d2*d2 + d4*d4);
}

__device__ __forceinline__ float pairdist(const float m1[6], const float m2[6]) {
    float L1[6], L2[6];
    logm3(m1, L1);
    logm3(m2, L2);
    return fnorm2_diff(L1, L2);
}

// One pair per thread, no loop: every thread's 12 loads issue immediately;
// the block dispatcher streams fresh blocks (fresh loads) through each CU
// while older blocks compute -> max memory-level parallelism, no convoys.
__global__ void __launch_bounds__(BLOCK)
le_partial(const float* __restrict__ D1, const float* __restrict__ D2,
           float* __restrict__ partial, int n, int npass) {
    const int tid = threadIdx.x;
    float acc = 0.0f;

    int i = (int)blockIdx.x * BLOCK + tid;
    int T = (int)gridDim.x * BLOCK;
    #pragma unroll 1
    for (int pass = 0; pass < npass; ++pass, i += T) {   // npass==1 normally
        if (i < n) {
            float m1[6], m2[6];
            load6i(D1, 9 * i, m1);
            load6i(D2, 9 * i, m2);
            acc += pairdist(m1, m2);
        }
    }

    // wave reduce (wave = 64)
    #pragma unroll
    for (int off = 32; off > 0; off >>= 1)
        acc += __shfl_down(acc, off, 64);
    __shared__ float wsum[BLOCK / 64];
    if ((tid & 63) == 0) wsum[tid >> 6] = acc;
    __syncthreads();
    if (tid == 0) {
        float s = 0.0f;
        #pragma unroll
        for (int j = 0; j < BLOCK / 64; ++j) s += wsum[j];
        partial[blockIdx.x] = s;
    }
}

__global__ void __launch_bounds__(FBLOCK)
le_final(const float* __restrict__ partial, int nparts,
         float* __restrict__ out, double invN) {
    double s = 0.0;
    for (int i = threadIdx.x; i < nparts; i += FBLOCK)
        s += (double)partial[i];
    #pragma unroll
    for (int off = 32; off > 0; off >>= 1)
        s += __shfl_down(s, off, 64);
    __shared__ double ws[FBLOCK / 64];
    if ((threadIdx.x & 63) == 0) ws[threadIdx.x >> 6] = s;
    __syncthreads();
    if (threadIdx.x == 0) {
        double t = 0.0;
        #pragma unroll
        for (int i = 0; i < FBLOCK / 64; ++i) t += ws[i];
        out[0] = (float)(t * invN);
    }
}

extern "C" void kernel_launch(void* const* d_in, const int* in_sizes, int n_in,
                              void* d_out, int out_size, void* d_ws, size_t ws_size,
                              hipStream_t stream) {
    const float* D1 = (const float*)d_in[0];
    const float* D2 = (const float*)d_in[1];
    float* out = (float*)d_out;
    float* partial = (float*)d_ws;

    int n = in_sizes[0] / 9;
    int nblk = (n + BLOCK - 1) / BLOCK;           // one pair per thread

    int grid = nblk;
    int maxblocks = (int)(ws_size / sizeof(float));
    if (maxblocks > 0 && grid > maxblocks) grid = maxblocks;  // ws guard
    if (grid < 1) grid = 1;
    int npass = (nblk + grid - 1) / grid;          // ==1 unless ws-capped

    le_partial<<<grid, BLOCK, 0, stream>>>(D1, D2, partial, n, npass);
    le_final<<<1, FBLOCK, 0, stream>>>(partial, grid, out, 1.0 / (double)n);
}